// Round 13
// baseline (354.820 us; speedup 1.0000x reference)
//
#include <hip/hip_runtime.h>
#include <hip/hip_fp16.h>

#define BATCH 256
#define ICAPS 1152
#define OCAPS 10
#define OD    160
#define BLOCK 960          // 15 waves; o = t%10 is pass- and iteration-invariant
#define NPASS 12           // 12 * 96 rows = 1152
#define RPP   96           // complete rows per pass (960/10)
#define PSTR  20           // part stride (floats): <=2-way LDS banks
#define VSTR  20           // v stride (floats): kills even/odd-o 5-way conflicts

// One block per batch element; ONE x read per routing iteration (fused
// dot + softmax + weighted-sum). Thread t owns (row=p*96+t/10, o=t%10):
// 32B contiguous fp16 per thread per pass (wave=2KB contiguous), dot is
// thread-local, b-state in breg[12] registers, softmax via one-barrier LDS
// exchange among the pass's 96 complete rows, and the same loaded registers
// feed acc[16] += c*x. Each thread re-reads exactly the x16 bytes it wrote
// in pass 0 (same u = p*960+t mapping) -> no cross-thread coherence needed.
__global__ __launch_bounds__(BLOCK, 1)
void k_fused(const float* __restrict__ x, __half* __restrict__ x16,
             float* __restrict__ out) {
    __shared__ float bc[NPASS][BLOCK];             // 46 KB per-pass logits
    __shared__ float part[BLOCK * PSTR];           // 76.8 KB per-thread partials
    __shared__ __align__(16) float v_pad[OCAPS * VSTR];

    const int b  = blockIdx.x;
    const int t  = threadIdx.x;
    const int o  = t % 10;
    const int rl = t / 10;                         // row-in-pass 0..95

    const float* xp = x + (size_t)b * (ICAPS * OD);
    __half*      hp = x16 + (size_t)b * (ICAPS * OD);

    float breg[NPASS];                             // accumulated routing logits
#pragma unroll
    for (int p = 0; p < NPASS; ++p) breg[p] = 0.f;

    float acc[16];
#pragma unroll
    for (int k = 0; k < 16; ++k) acc[k] = 0.f;

    // ---- pass 0: fp32 read (only HBM read of x), fp16 write, acc with c=1 ----
#pragma unroll
    for (int p = 0; p < NPASS; ++p) {
        const int u = p * BLOCK + t;
        const float* rp = xp + (size_t)u * 16;
        const float4 f0 = *(const float4*)(rp + 0);
        const float4 f1 = *(const float4*)(rp + 4);
        const float4 f2 = *(const float4*)(rp + 8);
        const float4 f3 = *(const float4*)(rp + 12);
        __half2 h0 = __floats2half2_rn(f0.x, f0.y), h1 = __floats2half2_rn(f0.z, f0.w);
        __half2 h2 = __floats2half2_rn(f1.x, f1.y), h3 = __floats2half2_rn(f1.z, f1.w);
        __half2 h4 = __floats2half2_rn(f2.x, f2.y), h5 = __floats2half2_rn(f2.z, f2.w);
        __half2 h6 = __floats2half2_rn(f3.x, f3.y), h7 = __floats2half2_rn(f3.z, f3.w);
        uint4 ua, ub;
        ua.x = *(unsigned*)&h0; ua.y = *(unsigned*)&h1;
        ua.z = *(unsigned*)&h2; ua.w = *(unsigned*)&h3;
        ub.x = *(unsigned*)&h4; ub.y = *(unsigned*)&h5;
        ub.z = *(unsigned*)&h6; ub.w = *(unsigned*)&h7;
        *(uint4*)(hp + (size_t)u * 16)     = ua;   // coalesced 32B/lane
        *(uint4*)(hp + (size_t)u * 16 + 8) = ub;
        acc[0]+=f0.x;  acc[1]+=f0.y;  acc[2]+=f0.z;  acc[3]+=f0.w;
        acc[4]+=f1.x;  acc[5]+=f1.y;  acc[6]+=f1.z;  acc[7]+=f1.w;
        acc[8]+=f2.x;  acc[9]+=f2.y;  acc[10]+=f2.z; acc[11]+=f2.w;
        acc[12]+=f3.x; acc[13]+=f3.y; acc[14]+=f3.z; acc[15]+=f3.w;
    }

    for (int it = 0; it <= 3; ++it) {
        // ---- per-thread acc -> LDS, reduce over the 96 rows sharing o, squash ----
#pragma unroll
        for (int k = 0; k < 16; k += 4) {
            float4 v4; v4.x=acc[k]; v4.y=acc[k+1]; v4.z=acc[k+2]; v4.w=acc[k+3];
            *(float4*)&part[t * PSTR + k] = v4;
        }
        __syncthreads();
        if (t < OD) {
            const int o2 = t >> 4, dd = t & 15;
            float s = 0.f;
#pragma unroll
            for (int r2 = 0; r2 < RPP; ++r2)
                s += part[(r2 * 10 + o2) * PSTR + dd];
            if (it == 0) s *= 0.1f;                // uniform c = softmax(0) = 0.1
            float sq = s * s;
#pragma unroll
            for (int mm = 1; mm < 16; mm <<= 1) sq += __shfl_xor(sq, mm, 64);
            const float sc = sqrtf(sq) / (1.f + sq);
            if (it == 3) out[(size_t)b * OD + t] = s * sc;
            else         v_pad[o2 * VSTR + dd] = s * sc;
        }
        __syncthreads();
        if (it == 3) break;

        // ---- fused pass: dot + b-update + softmax + weighted sum, 1 x-read ----
#pragma unroll
        for (int k = 0; k < 16; ++k) acc[k] = 0.f;
#pragma unroll
        for (int p = 0; p < NPASS; ++p) {
            const int u = p * BLOCK + t;
            const uint4 qa = *(const uint4*)(hp + (size_t)u * 16);
            const uint4 qb = *(const uint4*)(hp + (size_t)u * 16 + 8);
            const float4 w0 = *(const float4*)&v_pad[o * VSTR + 0];
            const float4 w1 = *(const float4*)&v_pad[o * VSTR + 4];
            const float4 w2 = *(const float4*)&v_pad[o * VSTR + 8];
            const float4 w3 = *(const float4*)&v_pad[o * VSTR + 12];
            float2 g;
            float d_ = 0.f;
            g = __half22float2(*(const __half2*)&qa.x); d_ += g.x*w0.x + g.y*w0.y;
            g = __half22float2(*(const __half2*)&qa.y); d_ += g.x*w0.z + g.y*w0.w;
            g = __half22float2(*(const __half2*)&qa.z); d_ += g.x*w1.x + g.y*w1.y;
            g = __half22float2(*(const __half2*)&qa.w); d_ += g.x*w1.z + g.y*w1.w;
            g = __half22float2(*(const __half2*)&qb.x); d_ += g.x*w2.x + g.y*w2.y;
            g = __half22float2(*(const __half2*)&qb.y); d_ += g.x*w2.z + g.y*w2.w;
            g = __half22float2(*(const __half2*)&qb.z); d_ += g.x*w3.x + g.y*w3.y;
            g = __half22float2(*(const __half2*)&qb.w); d_ += g.x*w3.z + g.y*w3.w;
            breg[p] += d_;                          // b accumulates across iterations
            bc[p][t] = breg[p];
            __syncthreads();
            const float* rowb = &bc[p][rl * 10];    // this row's 10 logits
            float m = rowb[0];
#pragma unroll
            for (int j = 1; j < 10; ++j) m = fmaxf(m, rowb[j]);
            float sum = 0.f;
#pragma unroll
            for (int j = 0; j < 10; ++j) sum += __expf(rowb[j] - m);
            const float c = __expf(breg[p] - m) / sum;
            g = __half22float2(*(const __half2*)&qa.x); acc[0] +=c*g.x; acc[1] +=c*g.y;
            g = __half22float2(*(const __half2*)&qa.y); acc[2] +=c*g.x; acc[3] +=c*g.y;
            g = __half22float2(*(const __half2*)&qa.z); acc[4] +=c*g.x; acc[5] +=c*g.y;
            g = __half22float2(*(const __half2*)&qa.w); acc[6] +=c*g.x; acc[7] +=c*g.y;
            g = __half22float2(*(const __half2*)&qb.x); acc[8] +=c*g.x; acc[9] +=c*g.y;
            g = __half22float2(*(const __half2*)&qb.y); acc[10]+=c*g.x; acc[11]+=c*g.y;
            g = __half22float2(*(const __half2*)&qb.z); acc[12]+=c*g.x; acc[13]+=c*g.y;
            g = __half22float2(*(const __half2*)&qb.w); acc[14]+=c*g.x; acc[15]+=c*g.y;
        }
    }
}

extern "C" void kernel_launch(void* const* d_in, const int* in_sizes, int n_in,
                              void* d_out, int out_size, void* d_ws, size_t ws_size,
                              hipStream_t stream) {
    const float* x = (const float*)d_in[0];
    __half* x16 = (__half*)d_ws;             // 94.4 MB fp16 copy of x
    float* vout = (float*)d_out;
    k_fused<<<BATCH, BLOCK, 0, stream>>>(x, x16, vout);
}